// Round 8
// baseline (91.190 us; speedup 1.0000x reference)
//
#include <hip/hip_runtime.h>
#include <hip/hip_bf16.h>
#include <math.h>

// ---------------------------------------------------------------------------
// RnCLoss: loss = -1/(n(n-1)) * sum_{i,k!=i} [ logit(i,k) - log denom(i,k) ]
//   logit(i,j) = 0.5*sqrt(max(2 - 2*g_ij, 0)),  g = normalized dot
//   denom(i,k) = sum_{j!=i, |l_i-l_j| >= |l_i-l_k|} exp(logit(i,j))
//
// No G matrix. k_prep packs Fn = f16(16 * f / ||f||) (512 KB, L2-resident);
// k_loss block i streams Fn, computes its own dot row via v_dot2_f32_f16 +
// wave reduce, then the proven R3 masked-denominator loop + counter finalize.
// ---------------------------------------------------------------------------

typedef _Float16 half2v __attribute__((ext_vector_type(2)));

static __device__ __forceinline__ float fdot2(half2v a, half2v b, float c) {
#if __has_builtin(__builtin_amdgcn_fdot2)
    return __builtin_amdgcn_fdot2(a, b, c, false);
#else
    return c + (float)a[0] * (float)b[0] + (float)a[1] * (float)b[1];
#endif
}

// Kernel 1: block b: norm of row b (fp32), write Fn[b] = f16(16*rn*row).
// Assumes d == 512 (256 threads x 2 elements).
__global__ __launch_bounds__(256) void k_prep(const float* __restrict__ F,
                                              _Float16* __restrict__ Fn,
                                              unsigned* __restrict__ ctr,
                                              int n, int d) {
    const int b = blockIdx.x;
    const int t = threadIdx.x;
    if (b == 0 && t == 0)
        __hip_atomic_store(ctr, 0u, __ATOMIC_RELAXED, __HIP_MEMORY_SCOPE_AGENT);

    __shared__ float red[4];
    const float* fr = F + (size_t)b * d;
    float2 v = *(const float2*)&fr[t * 2];
    float s = v.x * v.x + v.y * v.y;
    #pragma unroll
    for (int off = 32; off > 0; off >>= 1) s += __shfl_down(s, off);
    const int lane = t & 63, w = t >> 6;
    if (lane == 0) red[w] = s;
    __syncthreads();
    float tot = red[0] + red[1] + red[2] + red[3];  // all threads
    float scale = 16.0f * rsqrtf(tot);              // x16: dodge f16 denormals

    half2v h;
    h[0] = (_Float16)(v.x * scale);
    h[1] = (_Float16)(v.y * scale);
    *(half2v*)&Fn[(size_t)b * d + t * 2] = h;       // coalesced dword store
}

// Kernel 2: one block (256 thr, 4 waves) per row i.
//   dots:  wave w owns j in [w*128, w*128+128): coalesced 16B/lane stream of
//          Fn row j, 4x fdot2 vs registered fi chunk, 6x shfl_xor reduce.
//   post:  logits/exp/label-diff vectorized (2 j per thread).
//   mask:  R3's proven O(n) LDS-broadcast masked-denominator loop.
//   tail:  counter + last-block deterministic fixed-order reduction.
__global__ __launch_bounds__(256) void k_loss(const _Float16* __restrict__ Fn,
                                              const float* __restrict__ labels,
                                              float* __restrict__ row_sums,
                                              unsigned* __restrict__ ctr,
                                              float* __restrict__ out, int n) {
    const int i    = blockIdx.x;
    const int t    = threadIdx.x;
    const int lane = t & 63;
    const int w    = t >> 6;

    __shared__ float  lab_s[512];
    __shared__ float  gbuf[512];
    __shared__ float2 lde[512];     // (.x = label_diff, .y = exp_logit)
    __shared__ float  red[4];
    __shared__ int    flag_s;

    for (int j = t; j < n; j += 256) lab_s[j] = labels[j];

    // fi chunk: this lane's 8 columns of row i (d=512: 64 lanes x 8)
    const float4 fi4 = *(const float4*)&Fn[(size_t)i * 512 + lane * 8];
    const half2v a0 = __builtin_bit_cast(half2v, fi4.x);
    const half2v a1 = __builtin_bit_cast(half2v, fi4.y);
    const half2v a2 = __builtin_bit_cast(half2v, fi4.z);
    const half2v a3 = __builtin_bit_cast(half2v, fi4.w);

    // ---- dot phase: wave w sweeps its 128-row band (coalesced stream) ----
    const int jb = w * 128;
    #pragma unroll 2
    for (int jj = 0; jj < 128; ++jj) {
        const int j = jb + jj;
        float4 fj4 = *(const float4*)&Fn[(size_t)j * 512 + lane * 8];
        float acc = fdot2(a0, __builtin_bit_cast(half2v, fj4.x),
                    fdot2(a1, __builtin_bit_cast(half2v, fj4.y),
                    fdot2(a2, __builtin_bit_cast(half2v, fj4.z),
                    fdot2(a3, __builtin_bit_cast(half2v, fj4.w), 0.0f))));
        #pragma unroll
        for (int m = 32; m > 0; m >>= 1) acc += __shfl_xor(acc, m);
        if (lane == (jj & 63)) gbuf[j] = acc;   // one writer per j
    }
    __syncthreads();

    // ---- post-process: logits / exp / label-diff (2 j per thread) ----
    const float li = lab_s[i];
    float lgt[2], ldk[2];
    #pragma unroll
    for (int q = 0; q < 2; ++q) {
        const int j = t + q * 256;
        float g  = gbuf[j] * (1.0f / 256.0f);   // undo 16x16 scaling
        float sq = fmaxf(2.0f - 2.0f * g, 0.0f);
        float lg = 0.5f * sqrtf(sq);
        float e  = (j == i) ? 0.0f : __expf(lg);
        float ld = fabsf(li - lab_s[j]);
        lde[j] = make_float2(ld, e);
        lgt[q] = lg;
        ldk[q] = ld;    // bit-identical to lde[j].x -> exact >= semantics
    }
    __syncthreads();

    // ---- masked-denominator loop (proven R3) ----
    float s0 = 0.0f, s1 = 0.0f;
    #pragma unroll 8
    for (int j = 0; j < n; ++j) {
        float2 p = lde[j];  // wave-uniform address -> LDS broadcast
        s0 += (p.x >= ldk[0]) ? p.y : 0.0f;
        s1 += (p.x >= ldk[1]) ? p.y : 0.0f;
    }

    float acc = 0.0f;
    if (t != i)       acc += lgt[0] - __logf(s0);
    if (t + 256 != i) acc += lgt[1] - __logf(s1);

    // ---- block reduce + last-block deterministic final reduction ----
    #pragma unroll
    for (int off = 32; off > 0; off >>= 1) acc += __shfl_down(acc, off);
    if (lane == 0) red[w] = acc;
    __syncthreads();
    if (t == 0) {
        float rs = red[0] + red[1] + red[2] + red[3];
        __hip_atomic_store(&row_sums[i], rs, __ATOMIC_RELEASE,
                           __HIP_MEMORY_SCOPE_AGENT);
        unsigned prev = __hip_atomic_fetch_add(ctr, 1u, __ATOMIC_ACQ_REL,
                                               __HIP_MEMORY_SCOPE_AGENT);
        flag_s = (prev == (unsigned)(gridDim.x - 1));
    }
    __syncthreads();

    if (flag_s) {
        float s = 0.0f;
        for (int r = t; r < n; r += 256)
            s += __hip_atomic_load(&row_sums[r], __ATOMIC_ACQUIRE,
                                   __HIP_MEMORY_SCOPE_AGENT);
        #pragma unroll
        for (int off = 32; off > 0; off >>= 1) s += __shfl_down(s, off);
        if (lane == 0) red[w] = s;
        __syncthreads();
        if (t == 0) {
            float tot = red[0] + red[1] + red[2] + red[3];
            out[0] = -tot / ((float)n * ((float)n - 1.0f));
        }
    }
}

extern "C" void kernel_launch(void* const* d_in, const int* in_sizes, int n_in,
                              void* d_out, int out_size, void* d_ws, size_t ws_size,
                              hipStream_t stream) {
    const float* F      = (const float*)d_in[0];
    const float* labels = (const float*)d_in[1];
    int n = in_sizes[1];            // 512
    int d = in_sizes[0] / n;        // 512
    float* out = (float*)d_out;

    char* ws = (char*)d_ws;
    unsigned* ctr    = (unsigned*)ws;                 // 4 B
    float* row_sums  = (float*)(ws + 4096);           // n floats
    _Float16* Fn     = (_Float16*)(ws + 16384);       // n*d f16 (512 KB)

    k_prep<<<n, 256, 0, stream>>>(F, Fn, ctr, n, d);
    k_loss<<<n, 256, 0, stream>>>(Fn, labels, row_sums, ctr, out, n);
}

// Round 9
// 38.387 us; speedup vs baseline: 2.3756x; 2.3756x over previous
//
#include <hip/hip_runtime.h>
#include <hip/hip_bf16.h>
#include <math.h>

// ---------------------------------------------------------------------------
// RnCLoss: loss = -1/(n(n-1)) * sum_{i,k!=i} [ logit(i,k) - log denom(i,k) ]
//   logit(i,j) = 0.5*sqrt(max(2 - 2*G_ij*rsqrt(G_ii*G_jj), 0)), G = F F^T
//   denom(i,k) = sum_{j!=i, |l_i-l_j| >= |l_i-l_k|} exp(logit(i,j))
//
// Kernel 1 (65 blocks): blocks 0..63 = R3's proven bf16-MFMA GEMM (64x64
//   tiles) + diag + counter reset; block 64 = one-time bitonic sort of the
//   labels -> (mlab[], perm[])  (runs in parallel with the GEMM blocks).
// Kernel 2 (512 blocks): per-row loss. Key idea: over SORTED labels the
//   mask |l_i-l_j| >= D is two monotone runs around p = pos(i), so
//   denom = prefix[cL] + tot - prefix[rI] with cL/rI found by binary search
//   using the EXACT reference predicate fabsf(m-li) >= D on the monotone
//   halves -> identical mask set, O(log n) per k instead of O(n).
// ---------------------------------------------------------------------------

typedef __attribute__((ext_vector_type(8))) short          short8;
typedef __attribute__((ext_vector_type(8))) unsigned short ushort8;
typedef __attribute__((ext_vector_type(4))) float          f32x4;

static __device__ __forceinline__ unsigned short bf16_bits(float f) {
    __hip_bfloat16 h = __float2bfloat16(f);  // RNE
    return *reinterpret_cast<unsigned short*>(&h);
}

// Kernel 1: blocks 0..63: 64x64 GEMM tile (4 waves, 2x2 16x16 frags each,
// BK=64, fp32->bf16 in staging; G symmetric -> frag transpose harmless).
// Block 64: bitonic label sort (key=label, val=index).
__global__ __launch_bounds__(256) void k_gemm_sort(const float* __restrict__ F,
                                                   const float* __restrict__ labels,
                                                   float* __restrict__ G,
                                                   float* __restrict__ diag,
                                                   float* __restrict__ mlab,
                                                   int* __restrict__ perm,
                                                   unsigned* __restrict__ counter,
                                                   int n, int d) {
    const int b = blockIdx.x;
    const int t = threadIdx.x;
    if (b == 0 && t == 0) *counter = 0u;

    if (b == 64) {
        // ---- one-time bitonic sort of labels (n=512, 256 threads) ----
        __shared__ float sm[512];
        __shared__ int   sp[512];
        for (int j = t; j < n; j += 256) { sm[j] = labels[j]; sp[j] = j; }
        __syncthreads();
        for (int k = 2; k <= n; k <<= 1) {
            for (int s = k >> 1; s > 0; s >>= 1) {
                #pragma unroll
                for (int q = 0; q < 2; ++q) {
                    int x = t + q * 256;
                    int y = x ^ s;
                    if (y > x) {
                        float ax = sm[x], ay = sm[y];
                        int   px = sp[x], py = sp[y];
                        bool up = ((x & k) == 0);
                        if (up ? (ax > ay) : (ax < ay)) {
                            sm[x] = ay; sm[y] = ax;
                            sp[x] = py; sp[y] = px;
                        }
                    }
                }
                __syncthreads();
            }
        }
        for (int j = t; j < n; j += 256) { mlab[j] = sm[j]; perm[j] = sp[j]; }
        return;
    }

    // ---- GEMM path (identical to R3's proven kernel) ----
    __shared__ unsigned short Asm[64][72];
    __shared__ unsigned short Bsm[64][72];

    const int l  = t & 63;
    const int w  = t >> 6;
    const int wr = (w >> 1) << 5;
    const int wc = (w & 1) << 5;

    const int i0 = (b >> 3) << 6;
    const int j0 = (b & 7) << 6;

    const int sr = t >> 2;
    const int sc_ = (t & 3) << 4;

    const int fr = l & 15;
    const int fk = (l >> 4) << 3;

    f32x4 acc[2][2] = {};

    for (int k0 = 0; k0 < d; k0 += 64) {
        __syncthreads();

        const float4* pa = (const float4*)&F[(size_t)(i0 + sr) * d + k0 + sc_];
        const float4* pb = (const float4*)&F[(size_t)(j0 + sr) * d + k0 + sc_];
        float fa[16], fb[16];
        *(float4*)(fa + 0)  = pa[0]; *(float4*)(fa + 4)  = pa[1];
        *(float4*)(fa + 8)  = pa[2]; *(float4*)(fa + 12) = pa[3];
        *(float4*)(fb + 0)  = pb[0]; *(float4*)(fb + 4)  = pb[1];
        *(float4*)(fb + 8)  = pb[2]; *(float4*)(fb + 12) = pb[3];

        ushort8 va0, va1, vb0, vb1;
        #pragma unroll
        for (int e = 0; e < 8; ++e) {
            va0[e] = bf16_bits(fa[e]);     va1[e] = bf16_bits(fa[e + 8]);
            vb0[e] = bf16_bits(fb[e]);     vb1[e] = bf16_bits(fb[e + 8]);
        }
        *(ushort8*)&Asm[sr][sc_]     = va0;
        *(ushort8*)&Asm[sr][sc_ + 8] = va1;
        *(ushort8*)&Bsm[sr][sc_]     = vb0;
        *(ushort8*)&Bsm[sr][sc_ + 8] = vb1;

        __syncthreads();

        #pragma unroll
        for (int ks = 0; ks < 2; ++ks) {
            short8 af0 = *(const short8*)&Asm[wr + fr     ][ks * 32 + fk];
            short8 af1 = *(const short8*)&Asm[wr + 16 + fr][ks * 32 + fk];
            short8 bf0 = *(const short8*)&Bsm[wc + fr     ][ks * 32 + fk];
            short8 bf1 = *(const short8*)&Bsm[wc + 16 + fr][ks * 32 + fk];
            acc[0][0] = __builtin_amdgcn_mfma_f32_16x16x32_bf16(af0, bf0, acc[0][0], 0, 0, 0);
            acc[0][1] = __builtin_amdgcn_mfma_f32_16x16x32_bf16(af0, bf1, acc[0][1], 0, 0, 0);
            acc[1][0] = __builtin_amdgcn_mfma_f32_16x16x32_bf16(af1, bf0, acc[1][0], 0, 0, 0);
            acc[1][1] = __builtin_amdgcn_mfma_f32_16x16x32_bf16(af1, bf1, acc[1][1], 0, 0, 0);
        }
    }

    const int orow = (l >> 4) << 2;
    #pragma unroll
    for (int mi = 0; mi < 2; ++mi) {
        #pragma unroll
        for (int ni = 0; ni < 2; ++ni) {
            #pragma unroll
            for (int r = 0; r < 4; ++r) {
                int gi = i0 + wr + mi * 16 + orow + r;
                int gj = j0 + wc + ni * 16 + fr;
                float v = acc[mi][ni][r];
                G[(size_t)gi * n + gj] = v;
                if (gi == gj) diag[gi] = v;
            }
        }
    }
}

// Kernel 2: one block (256 threads) per row i.
__global__ __launch_bounds__(256) void k_loss(const float* __restrict__ labels,
                                              const float* __restrict__ G,
                                              const float* __restrict__ diag,
                                              const float* __restrict__ mlab,
                                              const int* __restrict__ perm,
                                              float* __restrict__ row_sums,
                                              unsigned* __restrict__ counter,
                                              float* __restrict__ out, int n) {
    const int i = blockIdx.x;
    const int t = threadIdx.x;
    __shared__ float m_s[512];     // sorted labels
    __shared__ int   pm_s[512];    // sorted -> natural index
    __shared__ float dg_s[512];    // diag
    __shared__ float en_s[512];    // e in natural order
    __shared__ float sc[512];      // e sorted, then inclusive prefix sums
    __shared__ float red[4];
    __shared__ int   p_s;          // sorted position of i
    __shared__ int   flag_s;

    for (int j = t; j < n; j += 256) {
        m_s[j]  = mlab[j];
        pm_s[j] = perm[j];
        dg_s[j] = diag[j];
    }
    __syncthreads();

    const float li = labels[i];
    const float di = dg_s[i];
    const float* Grow = G + (size_t)i * n;

    // ---- logits / exp (natural order); own-k label distances ----
    float lgt[2], ldk[2];
    #pragma unroll
    for (int q = 0; q < 2; ++q) {
        int j = t + q * 256;
        float g  = Grow[j] * rsqrtf(di * dg_s[j]);
        float sq = fmaxf(2.f - 2.f * g, 0.f);
        float lg = 0.5f * sqrtf(sq);
        en_s[j]  = (j == i) ? 0.f : expf(lg);
        lgt[q]   = lg;
        ldk[q]   = fabsf(li - labels[j]);
    }
    __syncthreads();

    // ---- gather e into label-sorted order; locate p ----
    #pragma unroll
    for (int q = 0; q < 2; ++q) {
        int jj  = t + q * 256;
        int src = pm_s[jj];
        sc[jj]  = en_s[src];
        if (src == i) p_s = jj;
    }
    __syncthreads();

    // ---- inclusive prefix scan over sorted e (Hillis-Steele, 9 rounds) ----
    for (int off = 1; off < n; off <<= 1) {
        float a0 = sc[t];       float b0 = (t >= off)       ? sc[t - off]       : 0.f;
        float a1 = sc[t + 256]; float b1 = (t + 256 >= off) ? sc[t + 256 - off] : 0.f;
        __syncthreads();
        sc[t]       = a0 + b0;
        sc[t + 256] = a1 + b1;
        __syncthreads();
    }
    const float tot = sc[n - 1];
    const int p = p_s;

    // ---- per k: denom via two monotone binary searches (exact mask) ----
    float acc = 0.f;
    #pragma unroll
    for (int q = 0; q < 2; ++q) {
        int kidx = t + q * 256;
        if (kidx == i) continue;
        float D = ldk[q];
        // left half [0, p]: dist non-increasing; cL = first idx with dist < D
        int lo = 0, hi = p + 1;
        while (lo < hi) {
            int mid = (lo + hi) >> 1;
            if (fabsf(m_s[mid] - li) >= D) lo = mid + 1; else hi = mid;
        }
        int cL = lo;                       // mask on left = [0, cL)
        // right half [p, n): dist non-decreasing; rI = first idx with dist >= D
        lo = p; hi = n;
        while (lo < hi) {
            int mid = (lo + hi) >> 1;
            if (fabsf(m_s[mid] - li) >= D) hi = mid; else lo = mid + 1;
        }
        int rI = lo;                       // mask on right = [rI, n)
        // only possible overlap is position p, where e = 0 -> harmless
        float S = (cL > 0 ? sc[cL - 1] : 0.f) + tot - (rI > 0 ? sc[rI - 1] : 0.f);
        acc += lgt[q] - logf(S);
    }

    // ---- block reduce + last-block deterministic final reduction ----
    #pragma unroll
    for (int off = 32; off > 0; off >>= 1) acc += __shfl_down(acc, off);
    const int lane = t & 63, wid = t >> 6;
    if (lane == 0) red[wid] = acc;
    __syncthreads();
    if (t == 0) {
        float rs = red[0] + red[1] + red[2] + red[3];
        __hip_atomic_store(&row_sums[i], rs, __ATOMIC_RELEASE,
                           __HIP_MEMORY_SCOPE_AGENT);
        unsigned prev = __hip_atomic_fetch_add(counter, 1u, __ATOMIC_ACQ_REL,
                                               __HIP_MEMORY_SCOPE_AGENT);
        flag_s = (prev == (unsigned)(gridDim.x - 1));
    }
    __syncthreads();

    if (flag_s) {
        float s = 0.f;
        for (int r = t; r < n; r += 256)
            s += __hip_atomic_load(&row_sums[r], __ATOMIC_ACQUIRE,
                                   __HIP_MEMORY_SCOPE_AGENT);
        #pragma unroll
        for (int off = 32; off > 0; off >>= 1) s += __shfl_down(s, off);
        if (lane == 0) red[wid] = s;
        __syncthreads();
        if (t == 0) {
            float tot2 = red[0] + red[1] + red[2] + red[3];
            out[0] = -tot2 / ((float)n * ((float)n - 1.0f));
        }
    }
}

extern "C" void kernel_launch(void* const* d_in, const int* in_sizes, int n_in,
                              void* d_out, int out_size, void* d_ws, size_t ws_size,
                              hipStream_t stream) {
    const float* F      = (const float*)d_in[0];
    const float* labels = (const float*)d_in[1];
    int n = in_sizes[1];            // 512
    int d = in_sizes[0] / n;        // 512
    float* out = (float*)d_out;

    char* ws = (char*)d_ws;
    unsigned* counter = (unsigned*)ws;                  // 4 B
    float* row_sums   = (float*)(ws + 4096);            // n floats
    float* diag       = (float*)(ws + 8192);            // n floats
    float* mlab       = (float*)(ws + 12288);           // n floats (sorted)
    int*   perm       = (int*)(ws + 14336);             // n ints
    float* G          = (float*)(ws + 16384);           // n*n fp32

    k_gemm_sort<<<65, 256, 0, stream>>>(F, labels, G, diag, mlab, perm,
                                        counter, n, d);
    k_loss<<<n, 256, 0, stream>>>(labels, G, diag, mlab, perm,
                                  row_sums, counter, out, n);
}

// Round 10
// 38.038 us; speedup vs baseline: 2.3973x; 1.0092x over previous
//
#include <hip/hip_runtime.h>
#include <hip/hip_bf16.h>
#include <math.h>

// ---------------------------------------------------------------------------
// RnCLoss: loss = -1/(n(n-1)) * sum_{i, k!=i} [ logit(i,k) - log denom(i,k) ]
//   logit(i,j) = 0.5*sqrt(max(2 - 2*G_ij*rsqrt(G_ii*G_jj), 0)), G = F F^T
//   denom(i,k) = sum_{j!=i, |l_i-l_j| >= |l_i-l_k|} exp(logit(i,j))
//
// Kernel 1 (258 blocks):
//   blocks 0..255 : 32x32-tile bf16-MFMA GEMM (all CUs busy), register
//                   double-buffered staging (next K-tile loads in flight
//                   during MFMAs) + diag + counter reset.
//   blocks 256,257: brute-force stable label ranks (no sort network):
//                   rank(j) = #{x: l_x<l_j or (l_x==l_j and x<j)} ->
//                   mlab[rank]=l_j, perm[rank]=j. Parallel, sync-free.
// Kernel 2 (512 blocks): per-row loss; denominators via prefix sums over
//   label-sorted e + two monotone binary searches with the EXACT reference
//   predicate (mask set identical; only fp summation order differs).
//   Scan = wave-level shfl_up (2 syncs), not Hillis-Steele (18 syncs).
// ---------------------------------------------------------------------------

typedef __attribute__((ext_vector_type(8))) short          short8;
typedef __attribute__((ext_vector_type(8))) unsigned short ushort8;
typedef __attribute__((ext_vector_type(4))) float          f32x4;

static __device__ __forceinline__ unsigned short bf16_bits(float f) {
    __hip_bfloat16 h = __float2bfloat16(f);  // RNE
    return *reinterpret_cast<unsigned short*>(&h);
}

// Kernel 1 -------------------------------------------------------------------
__global__ __launch_bounds__(256) void k_gemm_rank(const float* __restrict__ F,
                                                   const float* __restrict__ labels,
                                                   float* __restrict__ G,
                                                   float* __restrict__ diag,
                                                   float* __restrict__ mlab,
                                                   int* __restrict__ perm,
                                                   unsigned* __restrict__ counter,
                                                   int n, int d) {
    const int b = blockIdx.x;
    const int t = threadIdx.x;
    if (b == 0 && t == 0) *counter = 0u;

    if (b >= 256) {
        // ---- brute-force stable ranks (blocks 256,257) ----
        __shared__ float ls[512];
        for (int x = t; x < n; x += 256) ls[x] = labels[x];
        __syncthreads();
        const int j = (b - 256) * 256 + t;
        const float lj = ls[j];
        int cnt = 0;
        #pragma unroll 8
        for (int x = 0; x < 512; ++x) {
            float lx = ls[x];                   // wave-uniform -> broadcast
            cnt += (lx < lj) || (lx == lj && x < j);
        }
        mlab[cnt] = lj;                          // ranks unique -> no race
        perm[cnt] = j;
        return;
    }

    // ---- GEMM path: 32x32 tile, 4 waves (one 16x16 frag each), BK=64 ----
    __shared__ unsigned short Asm[32][72];
    __shared__ unsigned short Bsm[32][72];

    const int l  = t & 63;
    const int w  = t >> 6;
    const int wr = (w >> 1) << 4;   // frag row base: 0/16
    const int wc = (w & 1) << 4;    // frag col base: 0/16

    const int i0 = (b >> 4) << 5;
    const int j0 = (b & 15) << 5;

    const int sr  = t >> 3;          // staging row 0..31
    const int sc8 = (t & 7) << 3;    // staging col 0,8,...,56

    const int fr = l & 15;
    const int fk = (l >> 4) << 3;

    const float* pa = &F[(size_t)(i0 + sr) * d + sc8];
    const float* pb = &F[(size_t)(j0 + sr) * d + sc8];

    // prologue: load K-tile 0 into registers
    float4 a0 = *(const float4*)(pa + 0), a1 = *(const float4*)(pa + 4);
    float4 b0 = *(const float4*)(pb + 0), b1 = *(const float4*)(pb + 4);

    f32x4 acc = {};

    for (int k0 = 0; k0 < d; k0 += 64) {
        // stage current regs -> bf16 LDS
        ushort8 va, vb;
        va[0] = bf16_bits(a0.x); va[1] = bf16_bits(a0.y);
        va[2] = bf16_bits(a0.z); va[3] = bf16_bits(a0.w);
        va[4] = bf16_bits(a1.x); va[5] = bf16_bits(a1.y);
        va[6] = bf16_bits(a1.z); va[7] = bf16_bits(a1.w);
        vb[0] = bf16_bits(b0.x); vb[1] = bf16_bits(b0.y);
        vb[2] = bf16_bits(b0.z); vb[3] = bf16_bits(b0.w);
        vb[4] = bf16_bits(b1.x); vb[5] = bf16_bits(b1.y);
        vb[6] = bf16_bits(b1.z); vb[7] = bf16_bits(b1.w);
        *(ushort8*)&Asm[sr][sc8] = va;
        *(ushort8*)&Bsm[sr][sc8] = vb;
        __syncthreads();

        // issue next K-tile loads (stay in flight during the MFMAs)
        const int kn = (k0 + 64 < d) ? k0 + 64 : k0;
        a0 = *(const float4*)(pa + kn + 0); a1 = *(const float4*)(pa + kn + 4);
        b0 = *(const float4*)(pb + kn + 0); b1 = *(const float4*)(pb + kn + 4);

        // compute: 2 k-subs x 1 frag
        #pragma unroll
        for (int ks = 0; ks < 2; ++ks) {
            short8 af = *(const short8*)&Asm[wr + fr][ks * 32 + fk];
            short8 bf = *(const short8*)&Bsm[wc + fr][ks * 32 + fk];
            acc = __builtin_amdgcn_mfma_f32_16x16x32_bf16(af, bf, acc, 0, 0, 0);
        }
        __syncthreads();   // frag reads done before next stage overwrites
    }

    // epilogue: C/D mapping col = lane&15, row = (lane>>4)*4 + r (G symmetric)
    const int orow = (l >> 4) << 2;
    #pragma unroll
    for (int r = 0; r < 4; ++r) {
        int gi = i0 + wr + orow + r;
        int gj = j0 + wc + fr;
        float v = acc[r];
        G[(size_t)gi * n + gj] = v;
        if (gi == gj) diag[gi] = v;
    }
}

// Kernel 2 -------------------------------------------------------------------
__global__ __launch_bounds__(256) void k_loss(const float* __restrict__ labels,
                                              const float* __restrict__ G,
                                              const float* __restrict__ diag,
                                              const float* __restrict__ mlab,
                                              const int* __restrict__ perm,
                                              float* __restrict__ row_sums,
                                              unsigned* __restrict__ counter,
                                              float* __restrict__ out, int n) {
    const int i    = blockIdx.x;
    const int t    = threadIdx.x;
    const int lane = t & 63;
    const int w    = t >> 6;

    __shared__ float lab_s[512];
    __shared__ float m_s[512];      // sorted labels
    __shared__ int   pm_s[512];     // sorted -> natural index
    __shared__ float dg_s[512];     // diag
    __shared__ float en_s[512];     // e in natural order
    __shared__ float sc[512];       // gathered e, then inclusive prefix sums
    __shared__ float wtot[4];
    __shared__ float red[4];
    __shared__ int   p_s;
    __shared__ int   flag_s;

    for (int j = t; j < n; j += 256) {
        lab_s[j] = labels[j];
        m_s[j]   = mlab[j];
        pm_s[j]  = perm[j];
        dg_s[j]  = diag[j];
    }
    __syncthreads();

    const float li = lab_s[i];
    const float di = dg_s[i];
    const float* Grow = G + (size_t)i * n;

    // ---- logits / exp (natural order); own-k label distances ----
    float lgt[2], ldk[2];
    #pragma unroll
    for (int q = 0; q < 2; ++q) {
        int j = t + q * 256;
        float g  = Grow[j] * rsqrtf(di * dg_s[j]);
        float sq = fmaxf(2.f - 2.f * g, 0.f);
        float lg = 0.5f * sqrtf(sq);
        en_s[j]  = (j == i) ? 0.f : expf(lg);
        lgt[q]   = lg;
        ldk[q]   = fabsf(li - lab_s[j]);
    }
    __syncthreads();

    // ---- gather e into label-sorted order; locate p = sorted pos of i ----
    #pragma unroll
    for (int q = 0; q < 2; ++q) {
        int jj  = t + q * 256;
        int src = pm_s[jj];
        sc[jj]  = en_s[src];
        if (src == i) p_s = jj;
    }
    __syncthreads();

    // ---- inclusive prefix scan: wave-level shfl_up (thread owns 2t,2t+1) ----
    {
        float e0 = sc[2 * t], e1 = sc[2 * t + 1];
        float ps = e0 + e1;
        #pragma unroll
        for (int m = 1; m < 64; m <<= 1) {
            float v = __shfl_up(ps, m);
            if (lane >= m) ps += v;
        }
        if (lane == 63) wtot[w] = ps;
        __syncthreads();
        float woff = 0.f;
        #pragma unroll
        for (int w2 = 0; w2 < 4; ++w2) woff += (w2 < w) ? wtot[w2] : 0.f;
        float inc1 = woff + ps;        // inclusive through 2t+1
        sc[2 * t]     = inc1 - e1;     // inclusive through 2t
        sc[2 * t + 1] = inc1;
        __syncthreads();
    }
    const float tot = wtot[0] + wtot[1] + wtot[2] + wtot[3];
    const int p = p_s;

    // ---- per k: denom via two monotone binary searches (exact mask) ----
    float acc = 0.f;
    #pragma unroll
    for (int q = 0; q < 2; ++q) {
        int kidx = t + q * 256;
        if (kidx == i) continue;
        float D = ldk[q];
        // left half [0, p]: dist non-increasing; cL = first idx with dist < D
        int lo = 0, hi = p + 1;
        while (lo < hi) {
            int mid = (lo + hi) >> 1;
            if (fabsf(m_s[mid] - li) >= D) lo = mid + 1; else hi = mid;
        }
        int cL = lo;                       // masked left = [0, cL)
        // right half [p, n): dist non-decreasing; rI = first idx with dist >= D
        lo = p; hi = n;
        while (lo < hi) {
            int mid = (lo + hi) >> 1;
            if (fabsf(m_s[mid] - li) >= D) hi = mid; else lo = mid + 1;
        }
        int rI = lo;                       // masked right = [rI, n)
        // overlap can only be position p where e = 0 -> harmless
        float S = (cL > 0 ? sc[cL - 1] : 0.f) + tot - (rI > 0 ? sc[rI - 1] : 0.f);
        acc += lgt[q] - logf(S);
    }

    // ---- block reduce + last-block deterministic final reduction ----
    #pragma unroll
    for (int off = 32; off > 0; off >>= 1) acc += __shfl_down(acc, off);
    if (lane == 0) red[w] = acc;
    __syncthreads();
    if (t == 0) {
        float rs = red[0] + red[1] + red[2] + red[3];
        __hip_atomic_store(&row_sums[i], rs, __ATOMIC_RELEASE,
                           __HIP_MEMORY_SCOPE_AGENT);
        unsigned prev = __hip_atomic_fetch_add(counter, 1u, __ATOMIC_ACQ_REL,
                                               __HIP_MEMORY_SCOPE_AGENT);
        flag_s = (prev == (unsigned)(gridDim.x - 1));
    }
    __syncthreads();

    if (flag_s) {
        float s = 0.f;
        for (int r = t; r < n; r += 256)
            s += __hip_atomic_load(&row_sums[r], __ATOMIC_ACQUIRE,
                                   __HIP_MEMORY_SCOPE_AGENT);
        #pragma unroll
        for (int off = 32; off > 0; off >>= 1) s += __shfl_down(s, off);
        if (lane == 0) red[w] = s;
        __syncthreads();
        if (t == 0) {
            float tot2 = red[0] + red[1] + red[2] + red[3];
            out[0] = -tot2 / ((float)n * ((float)n - 1.0f));
        }
    }
}

extern "C" void kernel_launch(void* const* d_in, const int* in_sizes, int n_in,
                              void* d_out, int out_size, void* d_ws, size_t ws_size,
                              hipStream_t stream) {
    const float* F      = (const float*)d_in[0];
    const float* labels = (const float*)d_in[1];
    int n = in_sizes[1];            // 512
    int d = in_sizes[0] / n;        // 512
    float* out = (float*)d_out;

    char* ws = (char*)d_ws;
    unsigned* counter = (unsigned*)ws;                  // 4 B
    float* row_sums   = (float*)(ws + 4096);            // n floats
    float* diag       = (float*)(ws + 8192);            // n floats
    float* mlab       = (float*)(ws + 12288);           // n floats (sorted)
    int*   perm       = (int*)(ws + 14336);             // n ints
    float* G          = (float*)(ws + 16384);           // n*n fp32

    k_gemm_rank<<<258, 256, 0, stream>>>(F, labels, G, diag, mlab, perm,
                                         counter, n, d);
    k_loss<<<n, 256, 0, stream>>>(labels, G, diag, mlab, perm,
                                  row_sums, counter, out, n);
}

// Round 11
// 37.404 us; speedup vs baseline: 2.4380x; 1.0170x over previous
//
#include <hip/hip_runtime.h>
#include <hip/hip_bf16.h>
#include <math.h>

// ---------------------------------------------------------------------------
// RnCLoss: loss = -1/(n(n-1)) * sum_{i, k!=i} [ logit(i,k) - log denom(i,k) ]
//   logit(i,j) = 0.5*sqrt(max(2 - 2*G_ij*rsqrt(G_ii*G_jj), 0)), G = F F^T
//   denom(i,k) = sum_{j!=i, |l_i-l_j| >= |l_i-l_k|} exp(logit(i,j))
//
// Kernel 1 (258 blocks, unchanged from R10):
//   blocks 0..255 : 32x32-tile bf16-MFMA GEMM, register double-buffered
//                   staging + diag + counter reset.
//   blocks 256,257: brute-force stable label ranks -> mlab[], perm[].
// Kernel 2 (512 blocks): per-row loss ENTIRELY IN SORTED DOMAIN.
//   Thread t owns sorted positions 2t, 2t+1 -> wave holds 128 consecutive
//   positions -> binary-search keys are monotone across lanes -> search
//   LDS reads are broadcast-mostly (conflict-free) instead of scattered.
//   denom = prefix[cL] + tot - prefix[rI], boundaries by binary search with
//   the EXACT reference predicate on the monotone halves around p.
// ---------------------------------------------------------------------------

typedef __attribute__((ext_vector_type(8))) short          short8;
typedef __attribute__((ext_vector_type(8))) unsigned short ushort8;
typedef __attribute__((ext_vector_type(4))) float          f32x4;

static __device__ __forceinline__ unsigned short bf16_bits(float f) {
    __hip_bfloat16 h = __float2bfloat16(f);  // RNE
    return *reinterpret_cast<unsigned short*>(&h);
}

// Kernel 1 (identical to R10) -------------------------------------------------
__global__ __launch_bounds__(256) void k_gemm_rank(const float* __restrict__ F,
                                                   const float* __restrict__ labels,
                                                   float* __restrict__ G,
                                                   float* __restrict__ diag,
                                                   float* __restrict__ mlab,
                                                   int* __restrict__ perm,
                                                   unsigned* __restrict__ counter,
                                                   int n, int d) {
    const int b = blockIdx.x;
    const int t = threadIdx.x;
    if (b == 0 && t == 0) *counter = 0u;

    if (b >= 256) {
        // ---- brute-force stable ranks (blocks 256,257) ----
        __shared__ float ls[512];
        for (int x = t; x < n; x += 256) ls[x] = labels[x];
        __syncthreads();
        const int j = (b - 256) * 256 + t;
        const float lj = ls[j];
        int cnt = 0;
        #pragma unroll 8
        for (int x = 0; x < 512; ++x) {
            float lx = ls[x];                   // wave-uniform -> broadcast
            cnt += (lx < lj) || (lx == lj && x < j);
        }
        mlab[cnt] = lj;                          // ranks unique -> no race
        perm[cnt] = j;
        return;
    }

    // ---- GEMM path: 32x32 tile, 4 waves (one 16x16 frag each), BK=64 ----
    __shared__ unsigned short Asm[32][72];
    __shared__ unsigned short Bsm[32][72];

    const int l  = t & 63;
    const int w  = t >> 6;
    const int wr = (w >> 1) << 4;   // frag row base: 0/16
    const int wc = (w & 1) << 4;    // frag col base: 0/16

    const int i0 = (b >> 4) << 5;
    const int j0 = (b & 15) << 5;

    const int sr  = t >> 3;          // staging row 0..31
    const int sc8 = (t & 7) << 3;    // staging col 0,8,...,56

    const int fr = l & 15;
    const int fk = (l >> 4) << 3;

    const float* pa = &F[(size_t)(i0 + sr) * d + sc8];
    const float* pb = &F[(size_t)(j0 + sr) * d + sc8];

    // prologue: load K-tile 0 into registers
    float4 a0 = *(const float4*)(pa + 0), a1 = *(const float4*)(pa + 4);
    float4 b0 = *(const float4*)(pb + 0), b1 = *(const float4*)(pb + 4);

    f32x4 acc = {};

    for (int k0 = 0; k0 < d; k0 += 64) {
        ushort8 va, vb;
        va[0] = bf16_bits(a0.x); va[1] = bf16_bits(a0.y);
        va[2] = bf16_bits(a0.z); va[3] = bf16_bits(a0.w);
        va[4] = bf16_bits(a1.x); va[5] = bf16_bits(a1.y);
        va[6] = bf16_bits(a1.z); va[7] = bf16_bits(a1.w);
        vb[0] = bf16_bits(b0.x); vb[1] = bf16_bits(b0.y);
        vb[2] = bf16_bits(b0.z); vb[3] = bf16_bits(b0.w);
        vb[4] = bf16_bits(b1.x); vb[5] = bf16_bits(b1.y);
        vb[6] = bf16_bits(b1.z); vb[7] = bf16_bits(b1.w);
        *(ushort8*)&Asm[sr][sc8] = va;
        *(ushort8*)&Bsm[sr][sc8] = vb;
        __syncthreads();

        // issue next K-tile loads (stay in flight during the MFMAs)
        const int kn = (k0 + 64 < d) ? k0 + 64 : k0;
        a0 = *(const float4*)(pa + kn + 0); a1 = *(const float4*)(pa + kn + 4);
        b0 = *(const float4*)(pb + kn + 0); b1 = *(const float4*)(pb + kn + 4);

        #pragma unroll
        for (int ks = 0; ks < 2; ++ks) {
            short8 af = *(const short8*)&Asm[wr + fr][ks * 32 + fk];
            short8 bf = *(const short8*)&Bsm[wc + fr][ks * 32 + fk];
            acc = __builtin_amdgcn_mfma_f32_16x16x32_bf16(af, bf, acc, 0, 0, 0);
        }
        __syncthreads();
    }

    const int orow = (l >> 4) << 2;
    #pragma unroll
    for (int r = 0; r < 4; ++r) {
        int gi = i0 + wr + orow + r;
        int gj = j0 + wc + fr;
        float v = acc[r];
        G[(size_t)gi * n + gj] = v;
        if (gi == gj) diag[gi] = v;
    }
}

// Kernel 2: sorted-domain per-row loss ----------------------------------------
__global__ __launch_bounds__(256) void k_loss(const float* __restrict__ labels,
                                              const float* __restrict__ G,
                                              const float* __restrict__ diag,
                                              const float* __restrict__ mlab,
                                              const int* __restrict__ perm,
                                              float* __restrict__ row_sums,
                                              unsigned* __restrict__ counter,
                                              float* __restrict__ out, int n) {
    const int i    = blockIdx.x;
    const int t    = threadIdx.x;
    const int lane = t & 63;
    const int w    = t >> 6;

    __shared__ float m_s[512];      // sorted labels
    __shared__ int   pm_s[512];     // sorted pos -> natural index
    __shared__ float dg_s[512];     // diag, natural order
    __shared__ float g_s[512];      // G row i, natural order
    __shared__ float sc[512];       // inclusive prefix sums of sorted e
    __shared__ float wtot[4];
    __shared__ float red[4];
    __shared__ int   p_s;           // sorted position of i
    __shared__ int   flag_s;

    const float* Grow = G + (size_t)i * n;

    // ---- staging (vectorized float2/int2: thread t covers 2t, 2t+1) ----
    {
        float2 mv = ((const float2*)mlab)[t];
        int2   pv = ((const int2*)perm)[t];
        float2 dv = ((const float2*)diag)[t];
        float2 gv = ((const float2*)Grow)[t];
        m_s[2 * t] = mv.x;  m_s[2 * t + 1] = mv.y;
        pm_s[2 * t] = pv.x; pm_s[2 * t + 1] = pv.y;
        dg_s[2 * t] = dv.x; dg_s[2 * t + 1] = dv.y;
        g_s[2 * t] = gv.x;  g_s[2 * t + 1] = gv.y;
    }
    const float li = labels[i];     // uniform scalar load
    const float di = diag[i];
    __syncthreads();

    // ---- per sorted position q in {2t, 2t+1}: logit, e, D ----
    float lgt[2], Dk[2], ev[2];
    int   jn[2];
    #pragma unroll
    for (int qq = 0; qq < 2; ++qq) {
        const int q = 2 * t + qq;
        const int j = pm_s[q];                   // natural index
        jn[qq] = j;
        float gq = g_s[j];                       // scattered LDS (2/thread)
        float sq = fmaxf(2.f - 2.f * gq * rsqrtf(di * dg_s[j]), 0.f);
        float lg = 0.5f * sqrtf(sq);
        lgt[qq] = lg;
        ev[qq]  = (j == i) ? 0.f : __expf(lg);
        Dk[qq]  = fabsf(m_s[q] - li);            // == fabsf(li - labels[j])
        if (j == i) p_s = q;
    }

    // ---- inclusive prefix scan of sorted e (register-seeded shfl scan) ----
    {
        float ps = ev[0] + ev[1];
        #pragma unroll
        for (int m = 1; m < 64; m <<= 1) {
            float v = __shfl_up(ps, m);
            if (lane >= m) ps += v;
        }
        if (lane == 63) wtot[w] = ps;
        __syncthreads();
        float woff = 0.f;
        #pragma unroll
        for (int w2 = 0; w2 < 4; ++w2) woff += (w2 < w) ? wtot[w2] : 0.f;
        float inc1 = woff + ps;          // inclusive through 2t+1
        sc[2 * t]     = inc1 - ev[1];    // inclusive through 2t
        sc[2 * t + 1] = inc1;
        __syncthreads();
    }
    const float tot = wtot[0] + wtot[1] + wtot[2] + wtot[3];
    const int p = p_s;

    // ---- per q: denom via two monotone binary searches (exact mask).
    //      Lanes hold CONSECUTIVE q -> monotone keys -> broadcast-mostly mids.
    float acc = 0.f;
    #pragma unroll
    for (int qq = 0; qq < 2; ++qq) {
        if (jn[qq] == i) continue;
        const float D = Dk[qq];
        // left half [0, p]: dist non-increasing; cL = first idx with dist < D
        int lo = 0, hi = p + 1;
        while (lo < hi) {
            int mid = (lo + hi) >> 1;
            if (fabsf(m_s[mid] - li) >= D) lo = mid + 1; else hi = mid;
        }
        const int cL = lo;                 // masked left = [0, cL)
        // right half [p, n): dist non-decreasing; rI = first idx with dist >= D
        lo = p; hi = n;
        while (lo < hi) {
            int mid = (lo + hi) >> 1;
            if (fabsf(m_s[mid] - li) >= D) hi = mid; else lo = mid + 1;
        }
        const int rI = lo;                 // masked right = [rI, n)
        // overlap can only be position p where e = 0 -> harmless
        float S = (cL > 0 ? sc[cL - 1] : 0.f) + tot - (rI > 0 ? sc[rI - 1] : 0.f);
        acc += lgt[qq] - __logf(S);
    }

    // ---- block reduce + last-block deterministic final reduction ----
    #pragma unroll
    for (int off = 32; off > 0; off >>= 1) acc += __shfl_down(acc, off);
    if (lane == 0) red[w] = acc;
    __syncthreads();
    if (t == 0) {
        float rs = red[0] + red[1] + red[2] + red[3];
        __hip_atomic_store(&row_sums[i], rs, __ATOMIC_RELEASE,
                           __HIP_MEMORY_SCOPE_AGENT);
        unsigned prev = __hip_atomic_fetch_add(counter, 1u, __ATOMIC_ACQ_REL,
                                               __HIP_MEMORY_SCOPE_AGENT);
        flag_s = (prev == (unsigned)(gridDim.x - 1));
    }
    __syncthreads();

    if (flag_s) {
        float s = 0.f;
        for (int r = t; r < n; r += 256)
            s += __hip_atomic_load(&row_sums[r], __ATOMIC_ACQUIRE,
                                   __HIP_MEMORY_SCOPE_AGENT);
        #pragma unroll
        for (int off = 32; off > 0; off >>= 1) s += __shfl_down(s, off);
        if (lane == 0) red[w] = s;
        __syncthreads();
        if (t == 0) {
            float tot2 = red[0] + red[1] + red[2] + red[3];
            out[0] = -tot2 / ((float)n * ((float)n - 1.0f));
        }
    }
}

extern "C" void kernel_launch(void* const* d_in, const int* in_sizes, int n_in,
                              void* d_out, int out_size, void* d_ws, size_t ws_size,
                              hipStream_t stream) {
    const float* F      = (const float*)d_in[0];
    const float* labels = (const float*)d_in[1];
    int n = in_sizes[1];            // 512
    int d = in_sizes[0] / n;        // 512
    float* out = (float*)d_out;

    char* ws = (char*)d_ws;
    unsigned* counter = (unsigned*)ws;                  // 4 B
    float* row_sums   = (float*)(ws + 4096);            // n floats
    float* diag       = (float*)(ws + 8192);            // n floats
    float* mlab       = (float*)(ws + 12288);           // n floats (sorted)
    int*   perm       = (int*)(ws + 14336);             // n ints
    float* G          = (float*)(ws + 16384);           // n*n fp32

    k_gemm_rank<<<258, 256, 0, stream>>>(F, labels, G, diag, mlab, perm,
                                         counter, n, d);
    k_loss<<<n, 256, 0, stream>>>(labels, G, diag, mlab, perm,
                                  row_sums, counter, out, n);
}

// Round 12
// 27.380 us; speedup vs baseline: 3.3305x; 1.3661x over previous
//
#include <hip/hip_runtime.h>
#include <hip/hip_bf16.h>
#include <math.h>

// ---------------------------------------------------------------------------
// RnCLoss: loss = -1/(n(n-1)) * sum_{i, k!=i} [ logit(i,k) - log denom(i,k) ]
//   logit(i,j) = 0.5*sqrt(max(2 - 2*G_ij*rsqrt(G_ii*G_jj), 0)), G = F F^T
//   denom(i,k) = sum_{j!=i, |l_i-l_j| >= |l_i-l_k|} exp(logit(i,j))
//
// Kernel 1 (258 blocks, unchanged from R10/R11):
//   blocks 0..255 : 32x32-tile bf16-MFMA GEMM, register double-buffered
//                   staging + diag.
//   blocks 256,257: brute-force stable label ranks -> mlab[], perm[].
// Kernel 2 (512 blocks): sorted-domain per-row loss (R11 body). Ends with a
//   PLAIN store of row_sums[i] — the 512-deep same-cacheline atomic-RMW
//   finalize is gone (R4 calibration: ~100+ cyc per serialized RMW -> the
//   tail was ~10-25 us and invariant under all body optimizations).
// Kernel 3 (1 block): fixed-order final reduction (stream-ordered visibility).
// ---------------------------------------------------------------------------

typedef __attribute__((ext_vector_type(8))) short          short8;
typedef __attribute__((ext_vector_type(8))) unsigned short ushort8;
typedef __attribute__((ext_vector_type(4))) float          f32x4;

static __device__ __forceinline__ unsigned short bf16_bits(float f) {
    __hip_bfloat16 h = __float2bfloat16(f);  // RNE
    return *reinterpret_cast<unsigned short*>(&h);
}

// Kernel 1 -------------------------------------------------------------------
__global__ __launch_bounds__(256) void k_gemm_rank(const float* __restrict__ F,
                                                   const float* __restrict__ labels,
                                                   float* __restrict__ G,
                                                   float* __restrict__ diag,
                                                   float* __restrict__ mlab,
                                                   int* __restrict__ perm,
                                                   int n, int d) {
    const int b = blockIdx.x;
    const int t = threadIdx.x;

    if (b >= 256) {
        // ---- brute-force stable ranks (blocks 256,257) ----
        __shared__ float ls[512];
        for (int x = t; x < n; x += 256) ls[x] = labels[x];
        __syncthreads();
        const int j = (b - 256) * 256 + t;
        const float lj = ls[j];
        int cnt = 0;
        #pragma unroll 8
        for (int x = 0; x < 512; ++x) {
            float lx = ls[x];                   // wave-uniform -> broadcast
            cnt += (lx < lj) || (lx == lj && x < j);
        }
        mlab[cnt] = lj;                          // ranks unique -> no race
        perm[cnt] = j;
        return;
    }

    // ---- GEMM path: 32x32 tile, 4 waves (one 16x16 frag each), BK=64 ----
    __shared__ unsigned short Asm[32][72];
    __shared__ unsigned short Bsm[32][72];

    const int l  = t & 63;
    const int w  = t >> 6;
    const int wr = (w >> 1) << 4;   // frag row base: 0/16
    const int wc = (w & 1) << 4;    // frag col base: 0/16

    const int i0 = (b >> 4) << 5;
    const int j0 = (b & 15) << 5;

    const int sr  = t >> 3;          // staging row 0..31
    const int sc8 = (t & 7) << 3;    // staging col 0,8,...,56

    const int fr = l & 15;
    const int fk = (l >> 4) << 3;

    const float* pa = &F[(size_t)(i0 + sr) * d + sc8];
    const float* pb = &F[(size_t)(j0 + sr) * d + sc8];

    // prologue: load K-tile 0 into registers
    float4 a0 = *(const float4*)(pa + 0), a1 = *(const float4*)(pa + 4);
    float4 b0 = *(const float4*)(pb + 0), b1 = *(const float4*)(pb + 4);

    f32x4 acc = {};

    for (int k0 = 0; k0 < d; k0 += 64) {
        ushort8 va, vb;
        va[0] = bf16_bits(a0.x); va[1] = bf16_bits(a0.y);
        va[2] = bf16_bits(a0.z); va[3] = bf16_bits(a0.w);
        va[4] = bf16_bits(a1.x); va[5] = bf16_bits(a1.y);
        va[6] = bf16_bits(a1.z); va[7] = bf16_bits(a1.w);
        vb[0] = bf16_bits(b0.x); vb[1] = bf16_bits(b0.y);
        vb[2] = bf16_bits(b0.z); vb[3] = bf16_bits(b0.w);
        vb[4] = bf16_bits(b1.x); vb[5] = bf16_bits(b1.y);
        vb[6] = bf16_bits(b1.z); vb[7] = bf16_bits(b1.w);
        *(ushort8*)&Asm[sr][sc8] = va;
        *(ushort8*)&Bsm[sr][sc8] = vb;
        __syncthreads();

        // issue next K-tile loads (stay in flight during the MFMAs)
        const int kn = (k0 + 64 < d) ? k0 + 64 : k0;
        a0 = *(const float4*)(pa + kn + 0); a1 = *(const float4*)(pa + kn + 4);
        b0 = *(const float4*)(pb + kn + 0); b1 = *(const float4*)(pb + kn + 4);

        #pragma unroll
        for (int ks = 0; ks < 2; ++ks) {
            short8 af = *(const short8*)&Asm[wr + fr][ks * 32 + fk];
            short8 bf = *(const short8*)&Bsm[wc + fr][ks * 32 + fk];
            acc = __builtin_amdgcn_mfma_f32_16x16x32_bf16(af, bf, acc, 0, 0, 0);
        }
        __syncthreads();
    }

    const int orow = (l >> 4) << 2;
    #pragma unroll
    for (int r = 0; r < 4; ++r) {
        int gi = i0 + wr + orow + r;
        int gj = j0 + wc + fr;
        float v = acc[r];
        G[(size_t)gi * n + gj] = v;
        if (gi == gj) diag[gi] = v;
    }
}

// Kernel 2: sorted-domain per-row loss (R11 body, plain-store exit) ----------
__global__ __launch_bounds__(256) void k_loss(const float* __restrict__ labels,
                                              const float* __restrict__ G,
                                              const float* __restrict__ diag,
                                              const float* __restrict__ mlab,
                                              const int* __restrict__ perm,
                                              float* __restrict__ row_sums,
                                              int n) {
    const int i    = blockIdx.x;
    const int t    = threadIdx.x;
    const int lane = t & 63;
    const int w    = t >> 6;

    __shared__ float m_s[512];      // sorted labels
    __shared__ int   pm_s[512];     // sorted pos -> natural index
    __shared__ float dg_s[512];     // diag, natural order
    __shared__ float g_s[512];      // G row i, natural order
    __shared__ float sc[512];       // inclusive prefix sums of sorted e
    __shared__ float wtot[4];
    __shared__ float red[4];
    __shared__ int   p_s;           // sorted position of i

    const float* Grow = G + (size_t)i * n;

    // ---- staging (vectorized float2/int2: thread t covers 2t, 2t+1) ----
    {
        float2 mv = ((const float2*)mlab)[t];
        int2   pv = ((const int2*)perm)[t];
        float2 dv = ((const float2*)diag)[t];
        float2 gv = ((const float2*)Grow)[t];
        m_s[2 * t] = mv.x;  m_s[2 * t + 1] = mv.y;
        pm_s[2 * t] = pv.x; pm_s[2 * t + 1] = pv.y;
        dg_s[2 * t] = dv.x; dg_s[2 * t + 1] = dv.y;
        g_s[2 * t] = gv.x;  g_s[2 * t + 1] = gv.y;
    }
    const float li = labels[i];     // uniform scalar load
    const float di = diag[i];
    __syncthreads();

    // ---- per sorted position q in {2t, 2t+1}: logit, e, D ----
    float lgt[2], Dk[2], ev[2];
    int   jn[2];
    #pragma unroll
    for (int qq = 0; qq < 2; ++qq) {
        const int q = 2 * t + qq;
        const int j = pm_s[q];                   // natural index
        jn[qq] = j;
        float gq = g_s[j];                       // scattered LDS (2/thread)
        float sq = fmaxf(2.f - 2.f * gq * rsqrtf(di * dg_s[j]), 0.f);
        float lg = 0.5f * sqrtf(sq);
        lgt[qq] = lg;
        ev[qq]  = (j == i) ? 0.f : __expf(lg);
        Dk[qq]  = fabsf(m_s[q] - li);            // == fabsf(li - labels[j])
        if (j == i) p_s = q;
    }

    // ---- inclusive prefix scan of sorted e (register-seeded shfl scan) ----
    {
        float ps = ev[0] + ev[1];
        #pragma unroll
        for (int m = 1; m < 64; m <<= 1) {
            float v = __shfl_up(ps, m);
            if (lane >= m) ps += v;
        }
        if (lane == 63) wtot[w] = ps;
        __syncthreads();
        float woff = 0.f;
        #pragma unroll
        for (int w2 = 0; w2 < 4; ++w2) woff += (w2 < w) ? wtot[w2] : 0.f;
        float inc1 = woff + ps;          // inclusive through 2t+1
        sc[2 * t]     = inc1 - ev[1];    // inclusive through 2t
        sc[2 * t + 1] = inc1;
        __syncthreads();
    }
    const float tot = wtot[0] + wtot[1] + wtot[2] + wtot[3];
    const int p = p_s;

    // ---- per q: denom via two monotone binary searches (exact mask).
    //      Lanes hold CONSECUTIVE q -> monotone keys -> broadcast-mostly mids.
    float acc = 0.f;
    #pragma unroll
    for (int qq = 0; qq < 2; ++qq) {
        if (jn[qq] == i) continue;
        const float D = Dk[qq];
        // left half [0, p]: dist non-increasing; cL = first idx with dist < D
        int lo = 0, hi = p + 1;
        while (lo < hi) {
            int mid = (lo + hi) >> 1;
            if (fabsf(m_s[mid] - li) >= D) lo = mid + 1; else hi = mid;
        }
        const int cL = lo;                 // masked left = [0, cL)
        // right half [p, n): dist non-decreasing; rI = first idx with dist >= D
        lo = p; hi = n;
        while (lo < hi) {
            int mid = (lo + hi) >> 1;
            if (fabsf(m_s[mid] - li) >= D) hi = mid; else lo = mid + 1;
        }
        const int rI = lo;                 // masked right = [rI, n)
        // overlap can only be position p where e = 0 -> harmless
        float S = (cL > 0 ? sc[cL - 1] : 0.f) + tot - (rI > 0 ? sc[rI - 1] : 0.f);
        acc += lgt[qq] - __logf(S);
    }

    // ---- block reduce; plain-store exit (no atomics, no RMW tail) ----
    #pragma unroll
    for (int off = 32; off > 0; off >>= 1) acc += __shfl_down(acc, off);
    if (lane == 0) red[w] = acc;
    __syncthreads();
    if (t == 0) row_sums[i] = red[0] + red[1] + red[2] + red[3];
}

// Kernel 3: fixed-order final reduction (1 block) -----------------------------
__global__ __launch_bounds__(256) void k_final(const float* __restrict__ row_sums,
                                               float* __restrict__ out, int n) {
    const int t = threadIdx.x;
    __shared__ float red[4];
    float s = 0.f;
    for (int r = t; r < n; r += 256) s += row_sums[r];
    #pragma unroll
    for (int off = 32; off > 0; off >>= 1) s += __shfl_down(s, off);
    const int lane = t & 63, w = t >> 6;
    if (lane == 0) red[w] = s;
    __syncthreads();
    if (t == 0) {
        float tot = red[0] + red[1] + red[2] + red[3];
        out[0] = -tot / ((float)n * ((float)n - 1.0f));
    }
}

extern "C" void kernel_launch(void* const* d_in, const int* in_sizes, int n_in,
                              void* d_out, int out_size, void* d_ws, size_t ws_size,
                              hipStream_t stream) {
    const float* F      = (const float*)d_in[0];
    const float* labels = (const float*)d_in[1];
    int n = in_sizes[1];            // 512
    int d = in_sizes[0] / n;        // 512
    float* out = (float*)d_out;

    char* ws = (char*)d_ws;
    float* row_sums   = (float*)(ws + 4096);            // n floats
    float* diag       = (float*)(ws + 8192);            // n floats
    float* mlab       = (float*)(ws + 12288);           // n floats (sorted)
    int*   perm       = (int*)(ws + 14336);             // n ints
    float* G          = (float*)(ws + 16384);           // n*n fp32

    k_gemm_rank<<<258, 256, 0, stream>>>(F, labels, G, diag, mlab, perm, n, d);
    k_loss<<<n, 256, 0, stream>>>(labels, G, diag, mlab, perm, row_sums, n);
    k_final<<<1, 256, 0, stream>>>(row_sums, out, n);
}

// Round 13
// 25.784 us; speedup vs baseline: 3.5367x; 1.0619x over previous
//
#include <hip/hip_runtime.h>
#include <hip/hip_bf16.h>
#include <math.h>

// ---------------------------------------------------------------------------
// RnCLoss: loss = -1/(n(n-1)) * sum_{i, k!=i} [ logit(i,k) - log denom(i,k) ]
//   logit(i,j) = 0.5*sqrt(max(2 - 2*G_ij*rsqrt(G_ii*G_jj), 0)), G = F F^T
//   denom(i,k) = sum_{j!=i, |l_i-l_j| >= |l_i-l_k|} exp(logit(i,j))
//
// Kernel 1 (258 blocks):
//   blocks 0..255 : 32x32-tile bf16-MFMA GEMM with SINGLE-SHOT K staging:
//     all 2x32x512 fp32 operands loaded in one coalesced burst (one latency
//     exposure, not 8), bf16-converted into a 64KB XOR-swizzled LDS image,
//     ONE __syncthreads, then 16 unrolled ds_read_b128+MFMA steps.
//     (R12's 8-iter loop had ~300cyc exposed L2 latency + 2 syncs per iter
//      at 1 block/CU -> was ~14us attributed; this removes both.)
//   blocks 256,257: brute-force stable label ranks -> mlab[], perm[]
//     (reuses the GEMM LDS pool to stay within the 64KB static limit).
// Kernel 2 (512 blocks): sorted-domain per-row loss (R11/R12 body, proven).
// Kernel 3 (1 block): fixed-order final reduction.
// ---------------------------------------------------------------------------

typedef __attribute__((ext_vector_type(8))) short          short8;
typedef __attribute__((ext_vector_type(4))) unsigned short ushort4v;
typedef __attribute__((ext_vector_type(4))) float          f32x4;

static __device__ __forceinline__ unsigned short bf16_bits(float f) {
    __hip_bfloat16 h = __float2bfloat16(f);  // RNE
    return *reinterpret_cast<unsigned short*>(&h);
}

// Kernel 1 -------------------------------------------------------------------
// Requires d == 512 (fixed by the problem's setup_inputs).
__global__ __launch_bounds__(256) void k_gemm_rank(const float* __restrict__ F,
                                                   const float* __restrict__ labels,
                                                   float* __restrict__ G,
                                                   float* __restrict__ diag,
                                                   float* __restrict__ mlab,
                                                   int* __restrict__ perm,
                                                   int n, int d) {
    // 64 KB LDS pool: A image [32][512] + B image [32][512] bf16 (XOR-swizzled)
    __shared__ unsigned short Asm[32][512];
    __shared__ unsigned short Bsm[32][512];

    const int b = blockIdx.x;
    const int t = threadIdx.x;

    if (b >= 256) {
        // ---- brute-force stable ranks (blocks 256,257); reuse LDS pool ----
        float* ls = (float*)&Asm[0][0];
        for (int x = t; x < n; x += 256) ls[x] = labels[x];
        __syncthreads();
        const int j = (b - 256) * 256 + t;
        const float lj = ls[j];
        int cnt = 0;
        #pragma unroll 8
        for (int x = 0; x < 512; ++x) {
            float lx = ls[x];                   // wave-uniform -> broadcast
            cnt += (lx < lj) || (lx == lj && x < j);
        }
        mlab[cnt] = lj;                          // ranks unique -> no race
        perm[cnt] = j;
        return;
    }

    // ---- GEMM: 32x32 tile, 4 waves (one 16x16 frag each), BK = 512 ----
    const int l  = t & 63;
    const int w  = t >> 6;
    const int wr = (w >> 1) << 4;   // frag row base: 0/16
    const int wc = (w & 1) << 4;    // frag col base: 0/16

    const int i0 = (b >> 4) << 5;
    const int j0 = (b & 15) << 5;

    const int fr = l & 15;          // frag row within 16x16
    const int fk = (l >> 4) << 3;   // frag k base: 0,8,16,24

    // ---- single-shot staging: 16 passes x (2 coalesced float4 loads) ----
    // pass p: linear idx = p*1024 + t*4  ->  row = idx>>9, col = idx&511
    // LDS col index XOR-swizzled at 16B granule: cu = col ^ ((row&7)<<3)
    // (bijective within each row; spreads frag-read rows across banks with
    //  zero padding so both images fit exactly in 64 KB)
    #pragma unroll
    for (int p = 0; p < 16; ++p) {
        const int idx = p * 1024 + t * 4;
        const int row = idx >> 9;
        const int col = idx & 511;
        float4 av = *(const float4*)&F[(size_t)(i0 + row) * 512 + col];
        float4 bv = *(const float4*)&F[(size_t)(j0 + row) * 512 + col];
        ushort4v ua, ub;
        ua[0] = bf16_bits(av.x); ua[1] = bf16_bits(av.y);
        ua[2] = bf16_bits(av.z); ua[3] = bf16_bits(av.w);
        ub[0] = bf16_bits(bv.x); ub[1] = bf16_bits(bv.y);
        ub[2] = bf16_bits(bv.z); ub[3] = bf16_bits(bv.w);
        const int cu = col ^ ((row & 7) << 3);
        *(ushort4v*)&Asm[row][cu] = ua;
        *(ushort4v*)&Bsm[row][cu] = ub;
    }
    __syncthreads();   // the only barrier

    // ---- 16 K-steps: 2 x ds_read_b128 + 1 MFMA each, no further syncs ----
    const int rA = wr + fr;
    const int rB = wc + fr;
    const int sxA = (rA & 7) << 3;
    const int sxB = (rB & 7) << 3;
    f32x4 acc = {};
    #pragma unroll
    for (int ks = 0; ks < 16; ++ks) {
        const int colk = ks * 32 + fk;
        short8 af = *(const short8*)&Asm[rA][colk ^ sxA];
        short8 bf = *(const short8*)&Bsm[rB][colk ^ sxB];
        acc = __builtin_amdgcn_mfma_f32_16x16x32_bf16(af, bf, acc, 0, 0, 0);
    }

    // ---- epilogue: C/D mapping col=lane&15, row=(lane>>4)*4+r (G symm.) ----
    const int orow = (l >> 4) << 2;
    #pragma unroll
    for (int r = 0; r < 4; ++r) {
        int gi = i0 + wr + orow + r;
        int gj = j0 + wc + fr;
        float v = acc[r];
        G[(size_t)gi * n + gj] = v;
        if (gi == gj) diag[gi] = v;
    }
}

// Kernel 2: sorted-domain per-row loss (R12, proven) --------------------------
__global__ __launch_bounds__(256) void k_loss(const float* __restrict__ labels,
                                              const float* __restrict__ G,
                                              const float* __restrict__ diag,
                                              const float* __restrict__ mlab,
                                              const int* __restrict__ perm,
                                              float* __restrict__ row_sums,
                                              int n) {
    const int i    = blockIdx.x;
    const int t    = threadIdx.x;
    const int lane = t & 63;
    const int w    = t >> 6;

    __shared__ float m_s[512];      // sorted labels
    __shared__ int   pm_s[512];     // sorted pos -> natural index
    __shared__ float dg_s[512];     // diag, natural order
    __shared__ float g_s[512];      // G row i, natural order
    __shared__ float sc[512];       // inclusive prefix sums of sorted e
    __shared__ float wtot[4];
    __shared__ float red[4];
    __shared__ int   p_s;           // sorted position of i

    const float* Grow = G + (size_t)i * n;

    // ---- staging (vectorized float2/int2: thread t covers 2t, 2t+1) ----
    {
        float2 mv = ((const float2*)mlab)[t];
        int2   pv = ((const int2*)perm)[t];
        float2 dv = ((const float2*)diag)[t];
        float2 gv = ((const float2*)Grow)[t];
        m_s[2 * t] = mv.x;  m_s[2 * t + 1] = mv.y;
        pm_s[2 * t] = pv.x; pm_s[2 * t + 1] = pv.y;
        dg_s[2 * t] = dv.x; dg_s[2 * t + 1] = dv.y;
        g_s[2 * t] = gv.x;  g_s[2 * t + 1] = gv.y;
    }
    const float li = labels[i];     // uniform scalar load
    const float di = diag[i];
    __syncthreads();

    // ---- per sorted position q in {2t, 2t+1}: logit, e, D ----
    float lgt[2], Dk[2], ev[2];
    int   jn[2];
    #pragma unroll
    for (int qq = 0; qq < 2; ++qq) {
        const int q = 2 * t + qq;
        const int j = pm_s[q];                   // natural index
        jn[qq] = j;
        float gq = g_s[j];                       // scattered LDS (2/thread)
        float sq = fmaxf(2.f - 2.f * gq * rsqrtf(di * dg_s[j]), 0.f);
        float lg = 0.5f * sqrtf(sq);
        lgt[qq] = lg;
        ev[qq]  = (j == i) ? 0.f : __expf(lg);
        Dk[qq]  = fabsf(m_s[q] - li);            // == fabsf(li - labels[j])
        if (j == i) p_s = q;
    }

    // ---- inclusive prefix scan of sorted e (register-seeded shfl scan) ----
    {
        float ps = ev[0] + ev[1];
        #pragma unroll
        for (int m = 1; m < 64; m <<= 1) {
            float v = __shfl_up(ps, m);
            if (lane >= m) ps += v;
        }
        if (lane == 63) wtot[w] = ps;
        __syncthreads();
        float woff = 0.f;
        #pragma unroll
        for (int w2 = 0; w2 < 4; ++w2) woff += (w2 < w) ? wtot[w2] : 0.f;
        float inc1 = woff + ps;          // inclusive through 2t+1
        sc[2 * t]     = inc1 - ev[1];    // inclusive through 2t
        sc[2 * t + 1] = inc1;
        __syncthreads();
    }
    const float tot = wtot[0] + wtot[1] + wtot[2] + wtot[3];
    const int p = p_s;

    // ---- per q: denom via two monotone binary searches (exact mask).
    //      Lanes hold CONSECUTIVE q -> monotone keys -> broadcast-mostly mids.
    float acc = 0.f;
    #pragma unroll
    for (int qq = 0; qq < 2; ++qq) {
        if (jn[qq] == i) continue;
        const float D = Dk[qq];
        // left half [0, p]: dist non-increasing; cL = first idx with dist < D
        int lo = 0, hi = p + 1;
        while (lo < hi) {
            int mid = (lo + hi) >> 1;
            if (fabsf(m_s[mid] - li) >= D) lo = mid + 1; else hi = mid;
        }
        const int cL = lo;                 // masked left = [0, cL)
        // right half [p, n): dist non-decreasing; rI = first idx with dist >= D
        lo = p; hi = n;
        while (lo < hi) {
            int mid = (lo + hi) >> 1;
            if (fabsf(m_s[mid] - li) >= D) hi = mid; else lo = mid + 1;
        }
        const int rI = lo;                 // masked right = [rI, n)
        // overlap can only be position p where e = 0 -> harmless
        float S = (cL > 0 ? sc[cL - 1] : 0.f) + tot - (rI > 0 ? sc[rI - 1] : 0.f);
        acc += lgt[qq] - __logf(S);
    }

    // ---- block reduce; plain-store exit (no atomics, no RMW tail) ----
    #pragma unroll
    for (int off = 32; off > 0; off >>= 1) acc += __shfl_down(acc, off);
    if (lane == 0) red[w] = acc;
    __syncthreads();
    if (t == 0) row_sums[i] = red[0] + red[1] + red[2] + red[3];
}

// Kernel 3: fixed-order final reduction (1 block) -----------------------------
__global__ __launch_bounds__(256) void k_final(const float* __restrict__ row_sums,
                                               float* __restrict__ out, int n) {
    const int t = threadIdx.x;
    __shared__ float red[4];
    float s = 0.f;
    for (int r = t; r < n; r += 256) s += row_sums[r];
    #pragma unroll
    for (int off = 32; off > 0; off >>= 1) s += __shfl_down(s, off);
    const int lane = t & 63, w = t >> 6;
    if (lane == 0) red[w] = s;
    __syncthreads();
    if (t == 0) {
        float tot = red[0] + red[1] + red[2] + red[3];
        out[0] = -tot / ((float)n * ((float)n - 1.0f));
    }
}

extern "C" void kernel_launch(void* const* d_in, const int* in_sizes, int n_in,
                              void* d_out, int out_size, void* d_ws, size_t ws_size,
                              hipStream_t stream) {
    const float* F      = (const float*)d_in[0];
    const float* labels = (const float*)d_in[1];
    int n = in_sizes[1];            // 512
    int d = in_sizes[0] / n;        // 512
    float* out = (float*)d_out;

    char* ws = (char*)d_ws;
    float* row_sums   = (float*)(ws + 4096);            // n floats
    float* diag       = (float*)(ws + 8192);            // n floats
    float* mlab       = (float*)(ws + 12288);           // n floats (sorted)
    int*   perm       = (int*)(ws + 14336);             // n ints
    float* G          = (float*)(ws + 16384);           // n*n fp32

    k_gemm_rank<<<258, 256, 0, stream>>>(F, labels, G, diag, mlab, perm, n, d);
    k_loss<<<n, 256, 0, stream>>>(labels, G, diag, mlab, perm, row_sums, n);
    k_final<<<1, 256, 0, stream>>>(row_sums, out, n);
}